// Round 18
// baseline (568.273 us; speedup 1.0000x reference)
//
#include <hip/hip_runtime.h>
#include <hip/hip_bf16.h>

#define NT    10
#define NN    2048   // n_neurons
#define CA3C  2048
#define SEQ   1024
#define SPARS 0.05f
#define LRC   0.01f

typedef float          f32x4  __attribute__((ext_vector_type(4)));
typedef short          bf16x8 __attribute__((ext_vector_type(8)));
typedef unsigned short u16x4  __attribute__((ext_vector_type(4)));
typedef unsigned short u16x8  __attribute__((ext_vector_type(8)));

__device__ __forceinline__ unsigned short f2bf(float f) {   // RNE float->bf16 bits
    unsigned u = __float_as_uint(f);
    u += 0x7FFFu + ((u >> 16) & 1u);
    return (unsigned short)(u >> 16);
}
__device__ __forceinline__ float bf2f(unsigned short h) {
    return __uint_as_float(((unsigned)h) << 16);
}

// ---------------- split helper ------------------------------------------------------
__device__ __forceinline__ void split8(const float* __restrict__ src,
        unsigned short* __restrict__ hi, unsigned short* __restrict__ lo, long blk) {
    long i = (blk * 256 + threadIdx.x) * 8;
    f32x4 x0 = *(const f32x4*)(src + i);
    f32x4 x1 = *(const f32x4*)(src + i + 4);
    float xs[8] = {x0.x, x0.y, x0.z, x0.w, x1.x, x1.y, x1.z, x1.w};
    u16x8 h, l;
    #pragma unroll
    for (int j = 0; j < 8; ++j) {
        unsigned short hb = f2bf(xs[j]);
        h[j] = hb;
        l[j] = f2bf(xs[j] - bf2f(hb));
    }
    *(u16x8*)(hi + i) = h;
    if (lo) *(u16x8*)(lo + i) = l;
}

// ---------------- k1: fused hippo (blocks 0..2047) + input splits (2048..6143) -----
__global__ __launch_bounds__(256) void k_front(const int* __restrict__ tok,
        const float* __restrict__ sdr, const float* __restrict__ pos,
        unsigned short* __restrict__ Hh, unsigned* __restrict__ cnt,
        const float* __restrict__ w_hippo, unsigned short* __restrict__ Wh,
        unsigned short* __restrict__ Wl, const float* __restrict__ assoc,
        unsigned short* __restrict__ Sh) {
    long id = blockIdx.x;
    if (id == 0 && threadIdx.x == 0) *cnt = 0;
    if (id < 2048) {
        int s = (int)(id >> 1);
        int n = ((int)(id & 1) * 256 + threadIdx.x) * 4;
        const float* sp = sdr + (long)tok[s] * (NT * NN) + n;
        const float* pp = pos + (long)s * (NT * NN) + n;
        float a0 = 0.f, a1 = 0.f, a2 = 0.f, a3 = 0.f;
        #pragma unroll
        for (int t = 0; t < NT; ++t) {
            float4 sv = *(const float4*)(sp + t * NN);
            float4 pv = *(const float4*)(pp + t * NN);
            if (sv.x < SPARS) a0 += (pv.x < SPARS) ? 1.5f : 1.0f;
            if (sv.y < SPARS) a1 += (pv.y < SPARS) ? 1.5f : 1.0f;
            if (sv.z < SPARS) a2 += (pv.z < SPARS) ? 1.5f : 1.0f;
            if (sv.w < SPARS) a3 += (pv.w < SPARS) ? 1.5f : 1.0f;
        }
        u16x4 o = { f2bf(a0), f2bf(a1), f2bf(a2), f2bf(a3) };
        *(u16x4*)(Hh + (long)s * NN + n) = o;
    } else {
        long b = id - 2048;
        if (b < 2048) split8(w_hippo, Wh, Wl, b);
        else          split8(assoc, Sh, nullptr, b - 2048);
    }
}

// ---------------- MFMA GEMM body (R15/R17 proven, BM=128, templated BN) ------------
// FLAG=1: ballot-append |v|<1e-3 output indices to list (fp64 sign re-check later).
#define SPLIT_NONE 0
#define SPLIT_A    1
#define SPLIT_B    2

template<int MODE, int BN, int FLAG>
__device__ __forceinline__ void mg_body(int bx, int by,
        const unsigned short* __restrict__ A0, const unsigned short* __restrict__ A1,
        const unsigned short* __restrict__ Bh, const unsigned short* __restrict__ B1,
        float* __restrict__ C, int M, int N, int K,
        const float* __restrict__ Wadd, const float* __restrict__ af,
        unsigned* __restrict__ list, unsigned* __restrict__ cnt,
        unsigned short* __restrict__ LA, unsigned short* __restrict__ LB,
        unsigned short* __restrict__ LX) {
    constexpr int NTW = BN / 32;
    constexpr int XR  = (MODE == SPLIT_A) ? 128 : BN;
    int tid = threadIdx.x, wid = tid >> 6, l = tid & 63;
    int m0 = by * 128, n0 = bx * BN;
    int wr = wid >> 1, wc = wid & 1;
    int fr = l & 15, fk = l >> 4;
    f32x4 acc[4][NTW] = {};
    int srow = wid * 8 + (l >> 3);
    int scol = (l & 7) * 8;
    bf16x8 ra[4], rb[BN / 32], rx[XR / 32];
    #pragma unroll
    for (int i = 0; i < 4; ++i)
        ra[i] = *(const bf16x8*)(A0 + (long)(m0 + i * 32 + srow) * K + scol);
    #pragma unroll
    for (int i = 0; i < BN / 32; ++i)
        rb[i] = *(const bf16x8*)(Bh + (long)(n0 + i * 32 + srow) * K + scol);
    if (MODE == SPLIT_A)
        #pragma unroll
        for (int i = 0; i < XR / 32; ++i)
            rx[i] = *(const bf16x8*)(A1 + (long)(m0 + i * 32 + srow) * K + scol);
    if (MODE == SPLIT_B)
        #pragma unroll
        for (int i = 0; i < XR / 32; ++i)
            rx[i] = *(const bf16x8*)(B1 + (long)(n0 + i * 32 + srow) * K + scol);

    for (int k0 = 0; k0 < K; k0 += 64) {
        __syncthreads();
        #pragma unroll
        for (int i = 0; i < 4; ++i) *(bf16x8*)&LA[(i * 32 + srow) * 70 + scol] = ra[i];
        #pragma unroll
        for (int i = 0; i < BN / 32; ++i) *(bf16x8*)&LB[(i * 32 + srow) * 70 + scol] = rb[i];
        if (MODE != SPLIT_NONE)
            #pragma unroll
            for (int i = 0; i < XR / 32; ++i) *(bf16x8*)&LX[(i * 32 + srow) * 70 + scol] = rx[i];
        __syncthreads();
        if (k0 + 64 < K) {
            int kn = k0 + 64;
            #pragma unroll
            for (int i = 0; i < 4; ++i)
                ra[i] = *(const bf16x8*)(A0 + (long)(m0 + i * 32 + srow) * K + kn + scol);
            #pragma unroll
            for (int i = 0; i < BN / 32; ++i)
                rb[i] = *(const bf16x8*)(Bh + (long)(n0 + i * 32 + srow) * K + kn + scol);
            if (MODE == SPLIT_A)
                #pragma unroll
                for (int i = 0; i < XR / 32; ++i)
                    rx[i] = *(const bf16x8*)(A1 + (long)(m0 + i * 32 + srow) * K + kn + scol);
            if (MODE == SPLIT_B)
                #pragma unroll
                for (int i = 0; i < XR / 32; ++i)
                    rx[i] = *(const bf16x8*)(B1 + (long)(n0 + i * 32 + srow) * K + kn + scol);
        }
        #pragma unroll
        for (int ks = 0; ks < 2; ++ks) {
            bf16x8 av[4], bv[NTW], xv[4];
            #pragma unroll
            for (int t = 0; t < 4; ++t)
                av[t] = *(const bf16x8*)&LA[(wr * 64 + t * 16 + fr) * 70 + ks * 32 + fk * 8];
            #pragma unroll
            for (int t = 0; t < NTW; ++t)
                bv[t] = *(const bf16x8*)&LB[(wc * (BN / 2) + t * 16 + fr) * 70 + ks * 32 + fk * 8];
            if (MODE == SPLIT_A)
                #pragma unroll
                for (int t = 0; t < 4; ++t)
                    xv[t] = *(const bf16x8*)&LX[(wr * 64 + t * 16 + fr) * 70 + ks * 32 + fk * 8];
            if (MODE == SPLIT_B)
                #pragma unroll
                for (int t = 0; t < NTW; ++t)
                    xv[t] = *(const bf16x8*)&LX[(wc * (BN / 2) + t * 16 + fr) * 70 + ks * 32 + fk * 8];
            #pragma unroll
            for (int mt = 0; mt < 4; ++mt)
                #pragma unroll
                for (int nt = 0; nt < NTW; ++nt) {
                    acc[mt][nt] = __builtin_amdgcn_mfma_f32_16x16x32_bf16(av[mt], bv[nt], acc[mt][nt], 0, 0, 0);
                    if (MODE == SPLIT_A)
                        acc[mt][nt] = __builtin_amdgcn_mfma_f32_16x16x32_bf16(xv[mt], bv[nt], acc[mt][nt], 0, 0, 0);
                    if (MODE == SPLIT_B)
                        acc[mt][nt] = __builtin_amdgcn_mfma_f32_16x16x32_bf16(av[mt], xv[nt], acc[mt][nt], 0, 0, 0);
                }
        }
    }
    int drb = (l >> 4) * 4;
    #pragma unroll
    for (int mt = 0; mt < 4; ++mt)
        #pragma unroll
        for (int nt = 0; nt < NTW; ++nt)
            #pragma unroll
            for (int e = 0; e < 4; ++e) {
                int row = m0 + wr * 64 + mt * 16 + drb + e;
                int cc  = n0 + wc * (BN / 2) + nt * 16 + (l & 15);
                float v = acc[mt][nt][e];
                if (Wadd) v = fmaf(af[row], Wadd[(long)row * N + cc], v);
                C[(long)row * N + cc] = v;
                if (FLAG) {
                    bool f = fabsf(v) < 1e-3f;
                    unsigned long long mb = __ballot(f);
                    if (mb) {
                        unsigned base = 0;
                        if (l == 0) base = atomicAdd(cnt, (unsigned)__popcll(mb));
                        base = __shfl(base, 0, 64);
                        if (f) {
                            unsigned rank = (unsigned)__popcll(mb & ((1ull << l) - 1ull));
                            list[base + rank] = (unsigned)((long)row * N + cc);
                        }
                    }
                }
            }
}

template<int MODE, int BN, int FLAG>
__global__ __launch_bounds__(256, 1) void k_mgemm(
        const unsigned short* __restrict__ A0, const unsigned short* __restrict__ A1,
        const unsigned short* __restrict__ Bh, const unsigned short* __restrict__ B1,
        float* __restrict__ C, int M, int N, int K,
        const float* __restrict__ Wadd, const float* __restrict__ af,
        unsigned* __restrict__ list, unsigned* __restrict__ cnt) {
    constexpr int XR = (MODE == SPLIT_A) ? 128 : BN;
    __shared__ unsigned short LA[128 * 70];
    __shared__ unsigned short LB[BN * 70];
    __shared__ unsigned short LX[(MODE == SPLIT_NONE) ? 70 : XR * 70];
    mg_body<MODE, BN, FLAG>(blockIdx.x, blockIdx.y, A0, A1, Bh, B1, C, M, N, K,
                            Wadd, af, list, cnt, LA, LB, LX);
}

// ---------------- gram body: G fp32 + EXACT bf16 hi/lo split -----------------------
__device__ __forceinline__ void gram_body(int i, const unsigned* __restrict__ preT,
        float* __restrict__ G, unsigned short* __restrict__ Gbh,
        unsigned short* __restrict__ Gbl) {
    int t = threadIdx.x;
    int a0 = 0, a1 = 0, a2 = 0, a3 = 0;
    #pragma unroll 8
    for (int w = 0; w < 64; ++w) {
        unsigned ri = preT[w * SEQ + i];
        const unsigned* pr = preT + w * SEQ;
        a0 += __popc(ri & pr[t]);
        a1 += __popc(ri & pr[t + 256]);
        a2 += __popc(ri & pr[t + 512]);
        a3 += __popc(ri & pr[t + 768]);
    }
    long base = (long)i * SEQ;
    int vi[4] = {a0, a1, a2, a3};
    #pragma unroll
    for (int q = 0; q < 4; ++q) {
        long o = base + t + q * 256;
        float v = (float)vi[q];
        unsigned short h = f2bf(v);
        G[o] = v;
        Gbh[o] = h;
        Gbl[o] = f2bf(v - bf2f(h));
    }
}

// ---------------- k_mid: fused B0-GEMM (blocks 0..255) + gram (256..1279) ----------
__global__ __launch_bounds__(256, 1) void k_mid(const unsigned short* __restrict__ Sh,
        const unsigned short* __restrict__ Xb, float* __restrict__ B0f,
        const unsigned* __restrict__ preT, float* __restrict__ G,
        unsigned short* __restrict__ Gbh, unsigned short* __restrict__ Gbl) {
    __shared__ unsigned short LA[128 * 70];
    __shared__ unsigned short LB[64 * 70];
    int id = blockIdx.x;
    if (id < 256) {
        mg_body<SPLIT_NONE, 64, 0>(id & 15, id >> 4, Sh, nullptr, Xb, nullptr, B0f,
                                   2048, 1024, 2048, nullptr, nullptr, nullptr, nullptr,
                                   LA, LB, LA);
    } else {
        gram_body(id - 256, preT, G, Gbh, Gbl);
    }
}

// ---------------- fix64: one wave per flagged dot (fp64 exact re-dot) --------------
__global__ __launch_bounds__(64) void k_fix64(const unsigned* __restrict__ list,
        const unsigned* __restrict__ cnt, const unsigned short* __restrict__ Hh,
        const float* __restrict__ w, float* __restrict__ dots) {
    int lane = threadIdx.x;
    unsigned n = *cnt;
    for (unsigned idx = blockIdx.x; idx < n; idx += gridDim.x) {
        unsigned i = list[idx];
        int s = (int)(i >> 11), c = (int)(i & 2047);
        const unsigned short* hr = Hh + (long)s * NN;
        const float* wr = w + (long)c * NN;
        double a = 0.0;
        #pragma unroll
        for (int j = 0; j < 8; ++j) {
            int k = j * 256 + lane * 4;
            f32x4 wv = *(const f32x4*)(wr + k);
            u16x4 hv = *(const u16x4*)(hr + k);
            a += (double)bf2f(hv.x) * (double)wv.x + (double)bf2f(hv.y) * (double)wv.y
               + (double)bf2f(hv.z) * (double)wv.z + (double)bf2f(hv.w) * (double)wv.w;
        }
        #pragma unroll
        for (int o = 1; o < 64; o <<= 1) a += __shfl_xor(a, o, 64);
        if (lane == 0) dots[i] = (a > 0.0) ? 1.0f : -1.0f;
    }
}

// ---------------- k_packx: pack (0..255) + packpost (256..383) + transpose (384..895)
__global__ __launch_bounds__(256) void k_packx(const float* __restrict__ dots,
        unsigned* __restrict__ preT, float* __restrict__ popf,
        unsigned short* __restrict__ Xb, unsigned* __restrict__ postT,
        unsigned short* __restrict__ XbT) {
    int wid = threadIdx.x >> 6, lane = threadIdx.x & 63;
    if (blockIdx.x < 256) {
        int s = blockIdx.x * 4 + wid;
        const float* row = dots + (long)s * CA3C + lane * 32;
        unsigned short* xrow = Xb + (long)s * CA3C + lane * 32;
        unsigned m = 0;
        #pragma unroll
        for (int j4 = 0; j4 < 8; ++j4) {
            f32x4 v = *(const f32x4*)(row + j4 * 4);
            u16x4 xb;
            xb.x = v.x > 0.f ? 0x3F80 : 0; xb.y = v.y > 0.f ? 0x3F80 : 0;
            xb.z = v.z > 0.f ? 0x3F80 : 0; xb.w = v.w > 0.f ? 0x3F80 : 0;
            m |= (v.x > 0.f ? 1u : 0u) << (j4 * 4 + 0);
            m |= (v.y > 0.f ? 1u : 0u) << (j4 * 4 + 1);
            m |= (v.z > 0.f ? 1u : 0u) << (j4 * 4 + 2);
            m |= (v.w > 0.f ? 1u : 0u) << (j4 * 4 + 3);
            *(u16x4*)(xrow + j4 * 4) = xb;
        }
        preT[lane * SEQ + s] = m;
        int pc = __popc(m);
        #pragma unroll
        for (int o = 1; o < 64; o <<= 1) pc += __shfl_xor(pc, o, 64);
        if (lane == 0) popf[s] = (float)pc;
    } else if (blockIdx.x < 384) {
        __shared__ unsigned long long masks[4][64];
        int tile = (blockIdx.x - 256) * 4 + wid;   // 0..511
        int rg = tile & 31, sg = tile >> 5;
        int r0 = rg * 64;
        #pragma unroll 8
        for (int k = 0; k < 64; ++k) {
            int s = sg * 64 + k;
            float d = (s < SEQ - 1) ? dots[(long)(s + 1) * CA3C + r0 + lane] : -1.f;
            unsigned long long m = __ballot(d > 0.f);
            if (lane == 0) masks[wid][k] = m;
        }
        unsigned w0 = 0, w1 = 0;
        #pragma unroll
        for (int k = 0; k < 32; ++k) {
            w0 |= (unsigned)((masks[wid][k]      >> lane) & 1ull) << k;
            w1 |= (unsigned)((masks[wid][k + 32] >> lane) & 1ull) << k;
        }
        postT[(r0 + lane) * 32 + sg * 2]     = w0;
        postT[(r0 + lane) * 32 + sg * 2 + 1] = w1;
    } else {
        // transpose role: XbT[n][s] = (dots[s][n] > 0) in bf16, via LDS 64x64 tile.
        // Reads dots directly (same thresholded value as Xb) -> no Xb dependency.
        __shared__ unsigned short t[64][72];
        int tl = blockIdx.x - 384;                 // 0..511
        int s0 = (tl & 15) * 64, n0 = (tl >> 4) * 64;
        int tx = threadIdx.x & 63, ty = threadIdx.x >> 6;
        #pragma unroll
        for (int ii = 0; ii < 16; ++ii) {
            int i = ty + ii * 4;
            t[i][tx] = (dots[(long)(s0 + i) * CA3C + n0 + tx] > 0.f) ? 0x3F80 : 0;
        }
        __syncthreads();
        #pragma unroll
        for (int ii = 0; ii < 16; ++ii) {
            int i = ty + ii * 4;
            XbT[(long)(n0 + i) * SEQ + s0 + tx] = t[tx][i];
        }
    }
}

// ---------------- DPP-based full-wave (64 lane) sum --------------------------------
__device__ __forceinline__ float wave_sum64(float x) {
    #define DPPADD(ctrl, rmask) \
        x += __int_as_float(__builtin_amdgcn_update_dpp(0, __float_as_int(x), ctrl, rmask, 0xF, true))
    DPPADD(0xB1, 0xF);
    DPPADD(0x4E, 0xF);
    DPPADD(0x141, 0xF);
    DPPADD(0x140, 0xF);
    DPPADD(0x142, 0xA);
    DPPADD(0x143, 0xC);
    #undef DPPADD
    return __int_as_float(__builtin_amdgcn_readlane(__float_as_int(x), 63));
}

// ---------------- Phase D v5 (unchanged): MFMA inter-block + ping-pong -------------
__global__ __launch_bounds__(256) void k_scan2(const float* __restrict__ W0,
        const float* __restrict__ B0, const float* __restrict__ G,
        const unsigned short* __restrict__ Gbh, const unsigned short* __restrict__ Gbl,
        const unsigned* __restrict__ postT, const float* __restrict__ popf,
        unsigned short* __restrict__ Ch, unsigned short* __restrict__ Cl,
        float* __restrict__ alphaf) {
    __shared__ float Gd[64][68];
    __shared__ unsigned short BH[2][4096];
    __shared__ unsigned short BL[2][4096];
    __shared__ unsigned short CHL[8][1024];
    int tid = threadIdx.x, wid = tid >> 6, lane = tid & 63;
    int r = blockIdx.x * 4 + wid;
    int fr = lane & 15, fk = lane >> 4;
    int nl = tid >> 2, seg = tid & 3;
    const float* wr = W0 + (long)r * NN + lane * 32;
    f32x4 q0 = *(const f32x4*)(wr +  0), q1 = *(const f32x4*)(wr +  4);
    f32x4 q2 = *(const f32x4*)(wr +  8), q3 = *(const f32x4*)(wr + 12);
    f32x4 q4 = *(const f32x4*)(wr + 16), q5 = *(const f32x4*)(wr + 20);
    f32x4 q6 = *(const f32x4*)(wr + 24), q7 = *(const f32x4*)(wr + 28);
    f32x4 pp = q0*q0 + q1*q1 + q2*q2 + q3*q3 + q4*q4 + q5*q5 + q6*q6 + q7*q7;
    float nu = wave_sum64((pp.x + pp.y) + (pp.z + pp.w));
    float alpha = 1.f, inv_alpha = 1.f;
    { float t = fmaxf(nu, 1.f); alpha *= rsqrtf(t); inv_alpha *= sqrtf(t); nu = fminf(nu, 1.f); }
    float s0 = 1.f;

    bf16x8 ph0, ph1, pl0, pl1;
    for (int b = 0; b < 16; ++b) {
        __syncthreads();
        {
            const float* gs = G + (long)(b * 64 + nl) * SEQ + b * 64 + seg * 16;
            *(f32x4*)&Gd[nl][seg * 16 +  0] = *(const f32x4*)(gs +  0);
            *(f32x4*)&Gd[nl][seg * 16 +  4] = *(const f32x4*)(gs +  4);
            *(f32x4*)&Gd[nl][seg * 16 +  8] = *(const f32x4*)(gs +  8);
            *(f32x4*)&Gd[nl][seg * 16 + 12] = *(const f32x4*)(gs + 12);
        }
        if (b > 0) {
            const unsigned short* gh = Gbh + (long)(b * 64 + nl) * SEQ + seg * 16;
            const unsigned short* gl = Gbl + (long)(b * 64 + nl) * SEQ + seg * 16;
            ph0 = *(const bf16x8*)(gh); ph1 = *(const bf16x8*)(gh + 8);
            pl0 = *(const bf16x8*)(gl); pl1 = *(const bf16x8*)(gl + 8);
            *(bf16x8*)&BH[0][((seg * 2 + 0) * 64 + nl) * 8] = ph0;
            *(bf16x8*)&BH[0][((seg * 2 + 1) * 64 + nl) * 8] = ph1;
            *(bf16x8*)&BL[0][((seg * 2 + 0) * 64 + nl) * 8] = pl0;
            *(bf16x8*)&BL[0][((seg * 2 + 1) * 64 + nl) * 8] = pl1;
        }
        __syncthreads();
        f32x4 acc0 = {}, acc1 = {}, acc2 = {}, acc3 = {};
        for (int ch = 0; ch < b; ++ch) {
            if (ch + 1 < b) {
                const unsigned short* gh = Gbh + (long)(b * 64 + nl) * SEQ + (ch + 1) * 64 + seg * 16;
                const unsigned short* gl = Gbl + (long)(b * 64 + nl) * SEQ + (ch + 1) * 64 + seg * 16;
                ph0 = *(const bf16x8*)(gh); ph1 = *(const bf16x8*)(gh + 8);
                pl0 = *(const bf16x8*)(gl); pl1 = *(const bf16x8*)(gl + 8);
            }
            const unsigned short* bh = BH[ch & 1];
            const unsigned short* bl = BL[ch & 1];
            #pragma unroll
            for (int kt = 0; kt < 2; ++kt) {
                bf16x8 af = *(const bf16x8*)&CHL[fr & 7][ch * 64 + kt * 32 + fk * 8];
                #define MTILE(T, ACC) { \
                    bf16x8 vh = *(const bf16x8*)&bh[((kt * 4 + fk) * 64 + T * 16 + fr) * 8]; \
                    bf16x8 vl = *(const bf16x8*)&bl[((kt * 4 + fk) * 64 + T * 16 + fr) * 8]; \
                    ACC = __builtin_amdgcn_mfma_f32_16x16x32_bf16(af, vh, ACC, 0, 0, 0); \
                    ACC = __builtin_amdgcn_mfma_f32_16x16x32_bf16(af, vl, ACC, 0, 0, 0); }
                MTILE(0, acc0) MTILE(1, acc1) MTILE(2, acc2) MTILE(3, acc3)
                #undef MTILE
            }
            if (ch + 1 < b) {
                int nb = (ch + 1) & 1;
                *(bf16x8*)&BH[nb][((seg * 2 + 0) * 64 + nl) * 8] = ph0;
                *(bf16x8*)&BH[nb][((seg * 2 + 1) * 64 + nl) * 8] = ph1;
                *(bf16x8*)&BL[nb][((seg * 2 + 0) * 64 + nl) * 8] = pl0;
                *(bf16x8*)&BL[nb][((seg * 2 + 1) * 64 + nl) * 8] = pl1;
            }
            __syncthreads();
        }
        float t0 = (wid & 1) ? (acc0.z + acc0.w) : (acc0.x + acc0.y);
        float t1 = (wid & 1) ? (acc1.z + acc1.w) : (acc1.x + acc1.y);
        float t2 = (wid & 1) ? (acc2.z + acc2.w) : (acc2.x + acc2.y);
        float t3 = (wid & 1) ? (acc3.z + acc3.w) : (acc3.x + acc3.y);
        int sa = (((wid >> 1) * 16) + fr) * 4;
        float p0 = __int_as_float(__builtin_amdgcn_ds_bpermute(sa, __float_as_int(t0)));
        float p1 = __int_as_float(__builtin_amdgcn_ds_bpermute(sa, __float_as_int(t1)));
        float p2 = __int_as_float(__builtin_amdgcn_ds_bpermute(sa, __float_as_int(t2)));
        float p3 = __int_as_float(__builtin_amdgcn_ds_bpermute(sa, __float_as_int(t3)));
        float u = (fk == 0) ? p0 : (fk == 1) ? p1 : (fk == 2) ? p2 : p3;

        float myB0  = B0[(long)r * SEQ + b * 64 + lane];
        float mypop = popf[b * 64 + lane];
        unsigned long long pm;
        {   unsigned lo = postT[r * 32 + 2 * b], hi = postT[r * 32 + 2 * b + 1];
            pm = ((unsigned long long)(unsigned)__builtin_amdgcn_readfirstlane((int)hi) << 32)
               |  (unsigned long long)(unsigned)__builtin_amdgcn_readfirstlane((int)lo);
        }
        float dacc = fmaf(s0, myB0, u);
        float cj = 0.f;
        #pragma unroll
        for (int j = 0; j < 64; ++j) {
            if ((pm >> j) & 1ull) {
                float dot = __int_as_float(__builtin_amdgcn_readlane(__float_as_int(dacc), j));
                float pj  = __int_as_float(__builtin_amdgcn_readlane(__float_as_int(mypop), j));
                float c = LRC * inv_alpha;
                nu = fmaf(2.f * LRC, alpha * dot, fmaf(LRC * LRC, pj, nu));
                float t = fmaxf(nu, 1.f);
                alpha *= rsqrtf(t); inv_alpha *= sqrtf(t); nu = fminf(nu, 1.f);
                dacc = fmaf(c, Gd[j][lane], dacc);
                cj = (lane == j) ? c : cj;
            }
        }
        {   unsigned short hh = f2bf(cj);
            CHL[wid * 2 + 0][b * 64 + lane] = hh;
            CHL[wid * 2 + 1][b * 64 + lane] = f2bf(cj - bf2f(hh));
        }
        if (inv_alpha > 1e10f) {
            #pragma unroll 1
            for (int kk = 0; kk <= b; ++kk) {
                float v = (bf2f(CHL[wid * 2 + 0][kk * 64 + lane])
                         + bf2f(CHL[wid * 2 + 1][kk * 64 + lane])) * alpha;
                unsigned short hh = f2bf(v);
                CHL[wid * 2 + 0][kk * 64 + lane] = hh;
                CHL[wid * 2 + 1][kk * 64 + lane] = f2bf(v - bf2f(hh));
            }
            s0 *= alpha; alpha = 1.f; inv_alpha = 1.f;
        }
    }
    if (lane == 0) alphaf[r] = alpha * s0;
    #pragma unroll
    for (int kk = 0; kk < 16; ++kk) {
        float v = (bf2f(CHL[wid * 2 + 0][kk * 64 + lane])
                 + bf2f(CHL[wid * 2 + 1][kk * 64 + lane])) * alpha;
        unsigned short hh = f2bf(v);
        Ch[(long)r * SEQ + kk * 64 + lane] = hh;
        Cl[(long)r * SEQ + kk * 64 + lane] = f2bf(v - bf2f(hh));
    }
}

extern "C" void kernel_launch(void* const* d_in, const int* in_sizes, int n_in,
                              void* d_out, int out_size, void* d_ws, size_t ws_size,
                              hipStream_t stream) {
    const int*   tok     = (const int*)d_in[0];
    const float* sdr     = (const float*)d_in[1];
    const float* pos     = (const float*)d_in[2];
    const float* w_hippo = (const float*)d_in[3];
    const float* assoc   = (const float*)d_in[4];
    float* out = (float*)d_out;

    char* ws = (char*)d_ws;
    unsigned short* Hh  = (unsigned short*)(ws);                 // 0-4 MB; dead after fix64
    float*          G   = (float*)(ws);                          //   then G fp32 (4 MB)
    unsigned short* Wh  = (unsigned short*)(ws + (4l << 20));    // 4-12 MB
    unsigned short* Wl  = (unsigned short*)(ws + (12l << 20));   // 12-20 MB
    float*          dots= (float*)(ws + (20l << 20));            // 20-28 MB; then B0
    float*          B0f = dots;
    unsigned short* Xb  = (unsigned short*)(ws + (28l << 20));   // 28-32 MB
    unsigned short* XbT = (unsigned short*)(ws + (32l << 20));   // 32-36 MB
    unsigned* preT   = (unsigned*)(ws + (36l << 20));            // 256 KB
    unsigned* postT  = (unsigned*)(ws + (36l << 20) + 262144);   // 256 KB
    float*    popf   = (float*)(ws + (36l << 20) + 524288);      // 4 KB
    float*    alphaf = (float*)(ws + (36l << 20) + 532480);      // 8 KB
    unsigned* cnt    = (unsigned*)(ws + (37l << 20));            // 4 B
    unsigned* list   = (unsigned*)(ws + (37l << 20) + 4096);     // 1 MB
    unsigned short* Sh  = (unsigned short*)(ws + (40l << 20));   // 40-48 MB
    unsigned short* Ch  = (unsigned short*)(ws + (48l << 20));   // 48-52 MB
    unsigned short* Cl  = (unsigned short*)(ws + (52l << 20));   // 52-56 MB
    unsigned short* Gbh = (unsigned short*)(ws + (56l << 20));   // 56-58 MB
    unsigned short* Gbl = (unsigned short*)(ws + (58l << 20));   // 58-60 MB

    k_front                  <<<6144,         256, 0, stream>>>(tok, sdr, pos, Hh, cnt,
                                                                w_hippo, Wh, Wl, assoc, Sh);
    k_mgemm<SPLIT_B, 64, 1>  <<<dim3(32, 8),  256, 0, stream>>>(Hh, nullptr, Wh, Wl, dots,
                                                                1024, 2048, 2048, nullptr, nullptr,
                                                                list, cnt);
    k_fix64                  <<<2048,          64, 0, stream>>>(list, cnt, Hh, w_hippo, dots);
    k_packx                  <<<896,          256, 0, stream>>>(dots, preT, popf, Xb, postT, XbT);
    k_mid                    <<<1280,         256, 0, stream>>>(Sh, Xb, B0f, preT, G, Gbh, Gbl);
    k_scan2                  <<<512,          256, 0, stream>>>(assoc, B0f, G, Gbh, Gbl,
                                                                postT, popf, Ch, Cl, alphaf);
    k_mgemm<SPLIT_A, 128, 0> <<<dim3(16, 16), 256, 0, stream>>>(Ch, Cl, XbT, nullptr, out,
                                                                2048, 2048, 1024, assoc, alphaf,
                                                                nullptr, nullptr);
}

// Round 19
// 459.730 us; speedup vs baseline: 1.2361x; 1.2361x over previous
//
#include <hip/hip_runtime.h>
#include <hip/hip_bf16.h>

#define NT    10
#define NN    2048   // n_neurons
#define CA3C  2048
#define SEQ   1024
#define SPARS 0.05f
#define LRC   0.01f

typedef float          f32x4  __attribute__((ext_vector_type(4)));
typedef short          bf16x8 __attribute__((ext_vector_type(8)));
typedef unsigned short u16x4  __attribute__((ext_vector_type(4)));
typedef unsigned short u16x8  __attribute__((ext_vector_type(8)));

__device__ __forceinline__ unsigned short f2bf(float f) {   // RNE float->bf16 bits
    unsigned u = __float_as_uint(f);
    u += 0x7FFFu + ((u >> 16) & 1u);
    return (unsigned short)(u >> 16);
}
__device__ __forceinline__ float bf2f(unsigned short h) {
    return __uint_as_float(((unsigned)h) << 16);
}

// ---------------- split helper ------------------------------------------------------
__device__ __forceinline__ void split8(const float* __restrict__ src,
        unsigned short* __restrict__ hi, unsigned short* __restrict__ lo, long blk) {
    long i = (blk * 256 + threadIdx.x) * 8;
    f32x4 x0 = *(const f32x4*)(src + i);
    f32x4 x1 = *(const f32x4*)(src + i + 4);
    float xs[8] = {x0.x, x0.y, x0.z, x0.w, x1.x, x1.y, x1.z, x1.w};
    u16x8 h, l;
    #pragma unroll
    for (int j = 0; j < 8; ++j) {
        unsigned short hb = f2bf(xs[j]);
        h[j] = hb;
        l[j] = f2bf(xs[j] - bf2f(hb));
    }
    *(u16x8*)(hi + i) = h;
    if (lo) *(u16x8*)(lo + i) = l;
}

// ---------------- k1: fused hippo (blocks 0..2047) + input splits (2048..6143) -----
// R18 post-mortem: both aggressive fusions regressed (R16 +203us: BM=64 halved
// arithmetic intensity; R18 +108us: FLAG epilogue broke coalesced C-stores, and
// k_mid pinned latency-bound gram to the GEMM's 1-block/CU regime). This file is
// the exact 460us configuration (R17 input), re-established.
__global__ __launch_bounds__(256) void k_front(const int* __restrict__ tok,
        const float* __restrict__ sdr, const float* __restrict__ pos,
        unsigned short* __restrict__ Hh, unsigned* __restrict__ cnt,
        const float* __restrict__ w_hippo, unsigned short* __restrict__ Wh,
        unsigned short* __restrict__ Wl, const float* __restrict__ assoc,
        unsigned short* __restrict__ Sh) {
    long id = blockIdx.x;
    if (id == 0 && threadIdx.x == 0) *cnt = 0;
    if (id < 2048) {
        int s = (int)(id >> 1);
        int n = ((int)(id & 1) * 256 + threadIdx.x) * 4;
        const float* sp = sdr + (long)tok[s] * (NT * NN) + n;
        const float* pp = pos + (long)s * (NT * NN) + n;
        float a0 = 0.f, a1 = 0.f, a2 = 0.f, a3 = 0.f;
        #pragma unroll
        for (int t = 0; t < NT; ++t) {
            float4 sv = *(const float4*)(sp + t * NN);
            float4 pv = *(const float4*)(pp + t * NN);
            if (sv.x < SPARS) a0 += (pv.x < SPARS) ? 1.5f : 1.0f;
            if (sv.y < SPARS) a1 += (pv.y < SPARS) ? 1.5f : 1.0f;
            if (sv.z < SPARS) a2 += (pv.z < SPARS) ? 1.5f : 1.0f;
            if (sv.w < SPARS) a3 += (pv.w < SPARS) ? 1.5f : 1.0f;
        }
        u16x4 o = { f2bf(a0), f2bf(a1), f2bf(a2), f2bf(a3) };
        *(u16x4*)(Hh + (long)s * NN + n) = o;
    } else {
        long b = id - 2048;
        if (b < 2048) split8(w_hippo, Wh, Wl, b);
        else          split8(assoc, Sh, nullptr, b - 2048);
    }
}

// ---------------- MFMA GEMM (proven): BM=128, templated BN -------------------------
#define SPLIT_NONE 0
#define SPLIT_A    1
#define SPLIT_B    2

template<int MODE, int BN>
__global__ __launch_bounds__(256, 1) void k_mgemm(
        const unsigned short* __restrict__ A0, const unsigned short* __restrict__ A1,
        const unsigned short* __restrict__ Bh, const unsigned short* __restrict__ B1,
        float* __restrict__ C, int M, int N, int K,
        const float* __restrict__ Wadd, const float* __restrict__ af) {
    constexpr int NTW = BN / 32;            // N-tiles per wave (16-wide each)
    constexpr int XR  = (MODE == SPLIT_A) ? 128 : BN;   // LX rows
    __shared__ unsigned short LA[128 * 70];
    __shared__ unsigned short LB[BN * 70];
    __shared__ unsigned short LX[(MODE == SPLIT_NONE) ? 70 : XR * 70];
    int tid = threadIdx.x, wid = tid >> 6, l = tid & 63;
    int m0 = blockIdx.y * 128, n0 = blockIdx.x * BN;
    int wr = wid >> 1, wc = wid & 1;
    int fr = l & 15, fk = l >> 4;
    f32x4 acc[4][NTW] = {};
    int srow = wid * 8 + (l >> 3);          // 0..31; +i*32 -> rows
    int scol = (l & 7) * 8;
    bf16x8 ra[4], rb[BN / 32], rx[XR / 32];
    #pragma unroll
    for (int i = 0; i < 4; ++i)
        ra[i] = *(const bf16x8*)(A0 + (long)(m0 + i * 32 + srow) * K + scol);
    #pragma unroll
    for (int i = 0; i < BN / 32; ++i)
        rb[i] = *(const bf16x8*)(Bh + (long)(n0 + i * 32 + srow) * K + scol);
    if (MODE == SPLIT_A)
        #pragma unroll
        for (int i = 0; i < XR / 32; ++i)
            rx[i] = *(const bf16x8*)(A1 + (long)(m0 + i * 32 + srow) * K + scol);
    if (MODE == SPLIT_B)
        #pragma unroll
        for (int i = 0; i < XR / 32; ++i)
            rx[i] = *(const bf16x8*)(B1 + (long)(n0 + i * 32 + srow) * K + scol);

    for (int k0 = 0; k0 < K; k0 += 64) {
        __syncthreads();
        #pragma unroll
        for (int i = 0; i < 4; ++i) *(bf16x8*)&LA[(i * 32 + srow) * 70 + scol] = ra[i];
        #pragma unroll
        for (int i = 0; i < BN / 32; ++i) *(bf16x8*)&LB[(i * 32 + srow) * 70 + scol] = rb[i];
        if (MODE != SPLIT_NONE)
            #pragma unroll
            for (int i = 0; i < XR / 32; ++i) *(bf16x8*)&LX[(i * 32 + srow) * 70 + scol] = rx[i];
        __syncthreads();
        if (k0 + 64 < K) {
            int kn = k0 + 64;
            #pragma unroll
            for (int i = 0; i < 4; ++i)
                ra[i] = *(const bf16x8*)(A0 + (long)(m0 + i * 32 + srow) * K + kn + scol);
            #pragma unroll
            for (int i = 0; i < BN / 32; ++i)
                rb[i] = *(const bf16x8*)(Bh + (long)(n0 + i * 32 + srow) * K + kn + scol);
            if (MODE == SPLIT_A)
                #pragma unroll
                for (int i = 0; i < XR / 32; ++i)
                    rx[i] = *(const bf16x8*)(A1 + (long)(m0 + i * 32 + srow) * K + kn + scol);
            if (MODE == SPLIT_B)
                #pragma unroll
                for (int i = 0; i < XR / 32; ++i)
                    rx[i] = *(const bf16x8*)(B1 + (long)(n0 + i * 32 + srow) * K + kn + scol);
        }
        #pragma unroll
        for (int ks = 0; ks < 2; ++ks) {
            bf16x8 av[4], bv[NTW], xv[4];
            #pragma unroll
            for (int t = 0; t < 4; ++t)
                av[t] = *(const bf16x8*)&LA[(wr * 64 + t * 16 + fr) * 70 + ks * 32 + fk * 8];
            #pragma unroll
            for (int t = 0; t < NTW; ++t)
                bv[t] = *(const bf16x8*)&LB[(wc * (BN / 2) + t * 16 + fr) * 70 + ks * 32 + fk * 8];
            if (MODE == SPLIT_A)
                #pragma unroll
                for (int t = 0; t < 4; ++t)
                    xv[t] = *(const bf16x8*)&LX[(wr * 64 + t * 16 + fr) * 70 + ks * 32 + fk * 8];
            if (MODE == SPLIT_B)
                #pragma unroll
                for (int t = 0; t < NTW; ++t)
                    xv[t] = *(const bf16x8*)&LX[(wc * (BN / 2) + t * 16 + fr) * 70 + ks * 32 + fk * 8];
            #pragma unroll
            for (int mt = 0; mt < 4; ++mt)
                #pragma unroll
                for (int nt = 0; nt < NTW; ++nt) {
                    acc[mt][nt] = __builtin_amdgcn_mfma_f32_16x16x32_bf16(av[mt], bv[nt], acc[mt][nt], 0, 0, 0);
                    if (MODE == SPLIT_A)
                        acc[mt][nt] = __builtin_amdgcn_mfma_f32_16x16x32_bf16(xv[mt], bv[nt], acc[mt][nt], 0, 0, 0);
                    if (MODE == SPLIT_B)
                        acc[mt][nt] = __builtin_amdgcn_mfma_f32_16x16x32_bf16(av[mt], xv[nt], acc[mt][nt], 0, 0, 0);
                }
        }
    }
    int drb = (l >> 4) * 4;
    #pragma unroll
    for (int mt = 0; mt < 4; ++mt)
        #pragma unroll
        for (int nt = 0; nt < NTW; ++nt)
            #pragma unroll
            for (int e = 0; e < 4; ++e) {
                int row = m0 + wr * 64 + mt * 16 + drb + e;
                int cc  = n0 + wc * (BN / 2) + nt * 16 + (l & 15);
                float v = acc[mt][nt][e];
                if (Wadd) v = fmaf(af[row], Wadd[(long)row * N + cc], v);
                C[(long)row * N + cc] = v;
            }
}

// ---------------- fixup: flag+compact, then wave-parallel fp64 ---------------------
__global__ __launch_bounds__(256) void k_fixflag(const float* __restrict__ dots,
        unsigned* __restrict__ list, unsigned* __restrict__ cnt) {
    int i = blockIdx.x * 256 + threadIdx.x;
    int lane = threadIdx.x & 63;
    bool f = fabsf(dots[i]) < 1e-3f;
    unsigned long long m = __ballot(f);
    if (m == 0) return;
    unsigned b0 = 0;
    if (lane == 0) b0 = atomicAdd(cnt, (unsigned)__popcll(m));
    b0 = __shfl(b0, 0, 64);
    if (f) {
        unsigned rank = (unsigned)__popcll(m & ((1ull << lane) - 1ull));
        list[b0 + rank] = (unsigned)i;
    }
}

__global__ __launch_bounds__(64) void k_fix64(const unsigned* __restrict__ list,
        const unsigned* __restrict__ cnt, const unsigned short* __restrict__ Hh,
        const float* __restrict__ w, float* __restrict__ dots) {
    int lane = threadIdx.x;
    unsigned n = *cnt;
    for (unsigned idx = blockIdx.x; idx < n; idx += gridDim.x) {
        unsigned i = list[idx];
        int s = (int)(i >> 11), c = (int)(i & 2047);
        const unsigned short* hr = Hh + (long)s * NN;
        const float* wr = w + (long)c * NN;
        double a = 0.0;
        #pragma unroll
        for (int j = 0; j < 8; ++j) {
            int k = j * 256 + lane * 4;
            f32x4 wv = *(const f32x4*)(wr + k);
            u16x4 hv = *(const u16x4*)(hr + k);
            a += (double)bf2f(hv.x) * (double)wv.x + (double)bf2f(hv.y) * (double)wv.y
               + (double)bf2f(hv.z) * (double)wv.z + (double)bf2f(hv.w) * (double)wv.w;
        }
        #pragma unroll
        for (int o = 1; o < 64; o <<= 1) a += __shfl_xor(a, o, 64);
        if (lane == 0) dots[i] = (a > 0.0) ? 1.0f : -1.0f;
    }
}

// ---------------- fused pack (blocks 0..255) + packpost (256..383) -----------------
__global__ __launch_bounds__(256) void k_packx(const float* __restrict__ dots,
        unsigned* __restrict__ preT, float* __restrict__ popf,
        unsigned short* __restrict__ Xb, unsigned* __restrict__ postT) {
    int wid = threadIdx.x >> 6, lane = threadIdx.x & 63;
    if (blockIdx.x < 256) {
        int s = blockIdx.x * 4 + wid;
        const float* row = dots + (long)s * CA3C + lane * 32;
        unsigned short* xrow = Xb + (long)s * CA3C + lane * 32;
        unsigned m = 0;
        #pragma unroll
        for (int j4 = 0; j4 < 8; ++j4) {
            f32x4 v = *(const f32x4*)(row + j4 * 4);
            u16x4 xb;
            xb.x = v.x > 0.f ? 0x3F80 : 0; xb.y = v.y > 0.f ? 0x3F80 : 0;
            xb.z = v.z > 0.f ? 0x3F80 : 0; xb.w = v.w > 0.f ? 0x3F80 : 0;
            m |= (v.x > 0.f ? 1u : 0u) << (j4 * 4 + 0);
            m |= (v.y > 0.f ? 1u : 0u) << (j4 * 4 + 1);
            m |= (v.z > 0.f ? 1u : 0u) << (j4 * 4 + 2);
            m |= (v.w > 0.f ? 1u : 0u) << (j4 * 4 + 3);
            *(u16x4*)(xrow + j4 * 4) = xb;
        }
        preT[lane * SEQ + s] = m;
        int pc = __popc(m);
        #pragma unroll
        for (int o = 1; o < 64; o <<= 1) pc += __shfl_xor(pc, o, 64);
        if (lane == 0) popf[s] = (float)pc;
    } else {
        __shared__ unsigned long long masks[4][64];
        int tile = (blockIdx.x - 256) * 4 + wid;   // 0..511
        int rg = tile & 31, sg = tile >> 5;
        int r0 = rg * 64;
        #pragma unroll 8
        for (int k = 0; k < 64; ++k) {
            int s = sg * 64 + k;
            float d = (s < SEQ - 1) ? dots[(long)(s + 1) * CA3C + r0 + lane] : -1.f;
            unsigned long long m = __ballot(d > 0.f);
            if (lane == 0) masks[wid][k] = m;
        }
        unsigned w0 = 0, w1 = 0;
        #pragma unroll
        for (int k = 0; k < 32; ++k) {
            w0 |= (unsigned)((masks[wid][k]      >> lane) & 1ull) << k;
            w1 |= (unsigned)((masks[wid][k + 32] >> lane) & 1ull) << k;
        }
        postT[(r0 + lane) * 32 + sg * 2]     = w0;
        postT[(r0 + lane) * 32 + sg * 2 + 1] = w1;
    }
}

// ---------------- transpose Xb[s][n] -> XbT[n][s] (bf16) ---------------------------
__global__ __launch_bounds__(256) void k_transpose(const unsigned short* __restrict__ Xb,
        unsigned short* __restrict__ XbT) {
    __shared__ unsigned short t[64][72];
    int s0 = blockIdx.x * 64, n0 = blockIdx.y * 64;
    int tx = threadIdx.x & 63, ty = threadIdx.x >> 6;
    #pragma unroll
    for (int ii = 0; ii < 16; ++ii) {
        int i = ty + ii * 4;
        t[i][tx] = Xb[(long)(s0 + i) * CA3C + n0 + tx];
    }
    __syncthreads();
    #pragma unroll
    for (int ii = 0; ii < 16; ++ii) {
        int i = ty + ii * 4;
        XbT[(long)(n0 + i) * SEQ + s0 + tx] = t[tx][i];
    }
}

// ---------------- Gram: G fp32 + EXACT bf16 hi/lo split ----------------------------
__global__ __launch_bounds__(256) void k_gram(const unsigned* __restrict__ preT,
        float* __restrict__ G, unsigned short* __restrict__ Gbh,
        unsigned short* __restrict__ Gbl) {
    int i = blockIdx.x;
    int t = threadIdx.x;
    int a0 = 0, a1 = 0, a2 = 0, a3 = 0;
    #pragma unroll 8
    for (int w = 0; w < 64; ++w) {
        unsigned ri = preT[w * SEQ + i];
        const unsigned* pr = preT + w * SEQ;
        a0 += __popc(ri & pr[t]);
        a1 += __popc(ri & pr[t + 256]);
        a2 += __popc(ri & pr[t + 512]);
        a3 += __popc(ri & pr[t + 768]);
    }
    long base = (long)i * SEQ;
    int vi[4] = {a0, a1, a2, a3};
    #pragma unroll
    for (int q = 0; q < 4; ++q) {
        long o = base + t + q * 256;
        float v = (float)vi[q];
        unsigned short h = f2bf(v);
        G[o] = v;
        Gbh[o] = h;
        Gbl[o] = f2bf(v - bf2f(h));
    }
}

// ---------------- DPP-based full-wave (64 lane) sum --------------------------------
__device__ __forceinline__ float wave_sum64(float x) {
    #define DPPADD(ctrl, rmask) \
        x += __int_as_float(__builtin_amdgcn_update_dpp(0, __float_as_int(x), ctrl, rmask, 0xF, true))
    DPPADD(0xB1, 0xF);
    DPPADD(0x4E, 0xF);
    DPPADD(0x141, 0xF);
    DPPADD(0x140, 0xF);
    DPPADD(0x142, 0xA);
    DPPADD(0x143, 0xC);
    #undef DPPADD
    return __int_as_float(__builtin_amdgcn_readlane(__float_as_int(x), 63));
}

// ---------------- Phase D v5: MFMA inter-block + ping-pong -------------------------
__global__ __launch_bounds__(256) void k_scan2(const float* __restrict__ W0,
        const float* __restrict__ B0, const float* __restrict__ G,
        const unsigned short* __restrict__ Gbh, const unsigned short* __restrict__ Gbl,
        const unsigned* __restrict__ postT, const float* __restrict__ popf,
        unsigned short* __restrict__ Ch, unsigned short* __restrict__ Cl,
        float* __restrict__ alphaf) {
    __shared__ float Gd[64][68];
    __shared__ unsigned short BH[2][4096];
    __shared__ unsigned short BL[2][4096];
    __shared__ unsigned short CHL[8][1024];
    int tid = threadIdx.x, wid = tid >> 6, lane = tid & 63;
    int r = blockIdx.x * 4 + wid;
    int fr = lane & 15, fk = lane >> 4;
    int nl = tid >> 2, seg = tid & 3;
    const float* wr = W0 + (long)r * NN + lane * 32;
    f32x4 q0 = *(const f32x4*)(wr +  0), q1 = *(const f32x4*)(wr +  4);
    f32x4 q2 = *(const f32x4*)(wr +  8), q3 = *(const f32x4*)(wr + 12);
    f32x4 q4 = *(const f32x4*)(wr + 16), q5 = *(const f32x4*)(wr + 20);
    f32x4 q6 = *(const f32x4*)(wr + 24), q7 = *(const f32x4*)(wr + 28);
    f32x4 pp = q0*q0 + q1*q1 + q2*q2 + q3*q3 + q4*q4 + q5*q5 + q6*q6 + q7*q7;
    float nu = wave_sum64((pp.x + pp.y) + (pp.z + pp.w));
    float alpha = 1.f, inv_alpha = 1.f;
    { float t = fmaxf(nu, 1.f); alpha *= rsqrtf(t); inv_alpha *= sqrtf(t); nu = fminf(nu, 1.f); }
    float s0 = 1.f;

    bf16x8 ph0, ph1, pl0, pl1;
    for (int b = 0; b < 16; ++b) {
        __syncthreads();
        {
            const float* gs = G + (long)(b * 64 + nl) * SEQ + b * 64 + seg * 16;
            *(f32x4*)&Gd[nl][seg * 16 +  0] = *(const f32x4*)(gs +  0);
            *(f32x4*)&Gd[nl][seg * 16 +  4] = *(const f32x4*)(gs +  4);
            *(f32x4*)&Gd[nl][seg * 16 +  8] = *(const f32x4*)(gs +  8);
            *(f32x4*)&Gd[nl][seg * 16 + 12] = *(const f32x4*)(gs + 12);
        }
        if (b > 0) {
            const unsigned short* gh = Gbh + (long)(b * 64 + nl) * SEQ + seg * 16;
            const unsigned short* gl = Gbl + (long)(b * 64 + nl) * SEQ + seg * 16;
            ph0 = *(const bf16x8*)(gh); ph1 = *(const bf16x8*)(gh + 8);
            pl0 = *(const bf16x8*)(gl); pl1 = *(const bf16x8*)(gl + 8);
            *(bf16x8*)&BH[0][((seg * 2 + 0) * 64 + nl) * 8] = ph0;
            *(bf16x8*)&BH[0][((seg * 2 + 1) * 64 + nl) * 8] = ph1;
            *(bf16x8*)&BL[0][((seg * 2 + 0) * 64 + nl) * 8] = pl0;
            *(bf16x8*)&BL[0][((seg * 2 + 1) * 64 + nl) * 8] = pl1;
        }
        __syncthreads();
        f32x4 acc0 = {}, acc1 = {}, acc2 = {}, acc3 = {};
        for (int ch = 0; ch < b; ++ch) {
            if (ch + 1 < b) {
                const unsigned short* gh = Gbh + (long)(b * 64 + nl) * SEQ + (ch + 1) * 64 + seg * 16;
                const unsigned short* gl = Gbl + (long)(b * 64 + nl) * SEQ + (ch + 1) * 64 + seg * 16;
                ph0 = *(const bf16x8*)(gh); ph1 = *(const bf16x8*)(gh + 8);
                pl0 = *(const bf16x8*)(gl); pl1 = *(const bf16x8*)(gl + 8);
            }
            const unsigned short* bh = BH[ch & 1];
            const unsigned short* bl = BL[ch & 1];
            #pragma unroll
            for (int kt = 0; kt < 2; ++kt) {
                bf16x8 af = *(const bf16x8*)&CHL[fr & 7][ch * 64 + kt * 32 + fk * 8];
                #define MTILE(T, ACC) { \
                    bf16x8 vh = *(const bf16x8*)&bh[((kt * 4 + fk) * 64 + T * 16 + fr) * 8]; \
                    bf16x8 vl = *(const bf16x8*)&bl[((kt * 4 + fk) * 64 + T * 16 + fr) * 8]; \
                    ACC = __builtin_amdgcn_mfma_f32_16x16x32_bf16(af, vh, ACC, 0, 0, 0); \
                    ACC = __builtin_amdgcn_mfma_f32_16x16x32_bf16(af, vl, ACC, 0, 0, 0); }
                MTILE(0, acc0) MTILE(1, acc1) MTILE(2, acc2) MTILE(3, acc3)
                #undef MTILE
            }
            if (ch + 1 < b) {
                int nb = (ch + 1) & 1;
                *(bf16x8*)&BH[nb][((seg * 2 + 0) * 64 + nl) * 8] = ph0;
                *(bf16x8*)&BH[nb][((seg * 2 + 1) * 64 + nl) * 8] = ph1;
                *(bf16x8*)&BL[nb][((seg * 2 + 0) * 64 + nl) * 8] = pl0;
                *(bf16x8*)&BL[nb][((seg * 2 + 1) * 64 + nl) * 8] = pl1;
            }
            __syncthreads();
        }
        float t0 = (wid & 1) ? (acc0.z + acc0.w) : (acc0.x + acc0.y);
        float t1 = (wid & 1) ? (acc1.z + acc1.w) : (acc1.x + acc1.y);
        float t2 = (wid & 1) ? (acc2.z + acc2.w) : (acc2.x + acc2.y);
        float t3 = (wid & 1) ? (acc3.z + acc3.w) : (acc3.x + acc3.y);
        int sa = (((wid >> 1) * 16) + fr) * 4;
        float p0 = __int_as_float(__builtin_amdgcn_ds_bpermute(sa, __float_as_int(t0)));
        float p1 = __int_as_float(__builtin_amdgcn_ds_bpermute(sa, __float_as_int(t1)));
        float p2 = __int_as_float(__builtin_amdgcn_ds_bpermute(sa, __float_as_int(t2)));
        float p3 = __int_as_float(__builtin_amdgcn_ds_bpermute(sa, __float_as_int(t3)));
        float u = (fk == 0) ? p0 : (fk == 1) ? p1 : (fk == 2) ? p2 : p3;

        float myB0  = B0[(long)r * SEQ + b * 64 + lane];
        float mypop = popf[b * 64 + lane];
        unsigned long long pm;
        {   unsigned lo = postT[r * 32 + 2 * b], hi = postT[r * 32 + 2 * b + 1];
            pm = ((unsigned long long)(unsigned)__builtin_amdgcn_readfirstlane((int)hi) << 32)
               |  (unsigned long long)(unsigned)__builtin_amdgcn_readfirstlane((int)lo);
        }
        float dacc = fmaf(s0, myB0, u);
        float cj = 0.f;
        #pragma unroll
        for (int j = 0; j < 64; ++j) {
            if ((pm >> j) & 1ull) {
                float dot = __int_as_float(__builtin_amdgcn_readlane(__float_as_int(dacc), j));
                float pj  = __int_as_float(__builtin_amdgcn_readlane(__float_as_int(mypop), j));
                float c = LRC * inv_alpha;
                nu = fmaf(2.f * LRC, alpha * dot, fmaf(LRC * LRC, pj, nu));
                float t = fmaxf(nu, 1.f);
                alpha *= rsqrtf(t); inv_alpha *= sqrtf(t); nu = fminf(nu, 1.f);
                dacc = fmaf(c, Gd[j][lane], dacc);
                cj = (lane == j) ? c : cj;
            }
        }
        {   unsigned short hh = f2bf(cj);
            CHL[wid * 2 + 0][b * 64 + lane] = hh;
            CHL[wid * 2 + 1][b * 64 + lane] = f2bf(cj - bf2f(hh));
        }
        if (inv_alpha > 1e10f) {
            #pragma unroll 1
            for (int kk = 0; kk <= b; ++kk) {
                float v = (bf2f(CHL[wid * 2 + 0][kk * 64 + lane])
                         + bf2f(CHL[wid * 2 + 1][kk * 64 + lane])) * alpha;
                unsigned short hh = f2bf(v);
                CHL[wid * 2 + 0][kk * 64 + lane] = hh;
                CHL[wid * 2 + 1][kk * 64 + lane] = f2bf(v - bf2f(hh));
            }
            s0 *= alpha; alpha = 1.f; inv_alpha = 1.f;
        }
    }
    if (lane == 0) alphaf[r] = alpha * s0;
    #pragma unroll
    for (int kk = 0; kk < 16; ++kk) {
        float v = (bf2f(CHL[wid * 2 + 0][kk * 64 + lane])
                 + bf2f(CHL[wid * 2 + 1][kk * 64 + lane])) * alpha;
        unsigned short hh = f2bf(v);
        Ch[(long)r * SEQ + kk * 64 + lane] = hh;
        Cl[(long)r * SEQ + kk * 64 + lane] = f2bf(v - bf2f(hh));
    }
}

extern "C" void kernel_launch(void* const* d_in, const int* in_sizes, int n_in,
                              void* d_out, int out_size, void* d_ws, size_t ws_size,
                              hipStream_t stream) {
    const int*   tok     = (const int*)d_in[0];
    const float* sdr     = (const float*)d_in[1];
    const float* pos     = (const float*)d_in[2];
    const float* w_hippo = (const float*)d_in[3];
    const float* assoc   = (const float*)d_in[4];
    float* out = (float*)d_out;

    char* ws = (char*)d_ws;
    unsigned short* Hh  = (unsigned short*)(ws);                 // 0-4 MB; dead after fix64
    float*          G   = (float*)(ws);                          //   then G fp32 (4 MB)
    unsigned short* Wh  = (unsigned short*)(ws + (4l << 20));    // 4-12 MB
    unsigned short* Wl  = (unsigned short*)(ws + (12l << 20));   // 12-20 MB
    float*          dots= (float*)(ws + (20l << 20));            // 20-28 MB; then B0
    float*          B0f = dots;
    unsigned short* Xb  = (unsigned short*)(ws + (28l << 20));   // 28-32; dead after B0
    unsigned short* Gbh = Xb;                                    //   then G-bf16 hi (2 MB)
    unsigned short* Gbl = (unsigned short*)(ws + (30l << 20));   //   G-bf16 lo (2 MB)
    unsigned short* XbT = (unsigned short*)(ws + (32l << 20));   // 32-36 MB
    unsigned* preT   = (unsigned*)(ws + (36l << 20));            // 256 KB
    unsigned* postT  = (unsigned*)(ws + (36l << 20) + 262144);   // 256 KB
    float*    popf   = (float*)(ws + (36l << 20) + 524288);      // 4 KB
    float*    alphaf = (float*)(ws + (36l << 20) + 532480);      // 8 KB
    unsigned* cnt    = (unsigned*)(ws + (37l << 20));            // 4 B
    unsigned* list   = (unsigned*)(ws + (37l << 20) + 4096);     // 1 MB
    unsigned short* Sh  = (unsigned short*)(ws + (40l << 20));   // 40-48 MB (assoc bf16)
    unsigned short* Ch  = (unsigned short*)(ws + (48l << 20));   // 48-52 MB
    unsigned short* Cl  = (unsigned short*)(ws + (52l << 20));   // 52-56 MB

    k_front                <<<6144,         256, 0, stream>>>(tok, sdr, pos, Hh, cnt,
                                                              w_hippo, Wh, Wl, assoc, Sh);
    k_mgemm<SPLIT_B, 64>   <<<dim3(32, 8),  256, 0, stream>>>(Hh, nullptr, Wh, Wl, dots,
                                                              1024, 2048, 2048, nullptr, nullptr);
    k_fixflag              <<<8192,         256, 0, stream>>>(dots, list, cnt);
    k_fix64                <<<2048,          64, 0, stream>>>(list, cnt, Hh, w_hippo, dots);
    k_packx                <<<384,          256, 0, stream>>>(dots, preT, popf, Xb, postT);
    k_transpose            <<<dim3(16, 32), 256, 0, stream>>>(Xb, XbT);
    k_mgemm<SPLIT_NONE, 64><<<dim3(16, 16), 256, 0, stream>>>(Sh, nullptr, Xb, nullptr, B0f,
                                                              2048, 1024, 2048, nullptr, nullptr);
    k_gram                 <<<SEQ,          256, 0, stream>>>(preT, G, Gbh, Gbl);
    k_scan2                <<<512,          256, 0, stream>>>(assoc, B0f, G, Gbh, Gbl,
                                                              postT, popf, Ch, Cl, alphaf);
    k_mgemm<SPLIT_A, 128>  <<<dim3(16, 16), 256, 0, stream>>>(Ch, Cl, XbT, nullptr, out,
                                                              2048, 2048, 1024, assoc, alphaf);
}